// Round 6
// baseline (60.277 us; speedup 1.0000x reference)
//
#include <hip/hip_runtime.h>
#include <math.h>

// QConv2d: x (32,4,64,64) f32, params (4,8,16,16) f32 -> out (32,32,32,32) f32
// B=32 C=4 H=W=64, KH=KW=2 stride 2 -> px=py=32, NW=4, DIM=16, D=8, M=32768

#define NMAT 32          // C*D matrices
#define TAYLOR_N 9

// ---------------- Kernel 0: zero the output (rocclr memset path is slow)
__global__ __launch_bounds__(256) void zero_kernel(float4* __restrict__ out) {
    out[blockIdx.x * 256 + threadIdx.x] = make_float4(0.f, 0.f, 0.f, 0.f);
}

// ---------------- Kernel 1: W'[c*8+d][j][i] = expm(SH)[i][j] * (-i)^popc(i) ----
__global__ __launch_bounds__(256) void expm_kernel(const float* __restrict__ params,
                                                   float2* __restrict__ wp) {
    __shared__ float2 X[256];
    __shared__ float2 P0[256];
    __shared__ float2 P1[256];
    __shared__ float red[256];
    __shared__ float srow[16];
    __shared__ int ssexp;

    const int bid = blockIdx.x;      // c*8 + d
    const int tid = threadIdx.x;
    const int i = tid >> 4, j = tid & 15;

    const float* pm = params + bid * 256;
    float pij = pm[i * 16 + j];
    float pji = pm[j * 16 + i];
    float ar = pij - pji;   // asym -> real part of SH
    float ai = pij + pji;   // sym  -> imag part of SH
    red[tid] = fabsf(ar) + fabsf(ai);
    __syncthreads();
    if (j == 0) {
        float s = 0.f;
        for (int t = 0; t < 16; ++t) s += red[i * 16 + t];
        srow[i] = s;
    }
    __syncthreads();
    if (tid == 0) {
        float mx = 0.f;
        for (int t = 0; t < 16; ++t) mx = fmaxf(mx, srow[t]);
        int se = 0;
        while (mx > 0.5f && se < 40) { mx *= 0.5f; se++; }
        ssexp = se;
    }
    __syncthreads();
    const int sexp = ssexp;
    const float scale = exp2f((float)(-sexp));
    const float xr = ar * scale, xi = ai * scale;
    X[tid] = make_float2(xr, xi);
    // P = I + X/N
    float2 p = make_float2(xr / TAYLOR_N + ((i == j) ? 1.f : 0.f), xi / TAYLOR_N);
    P0[tid] = p;
    __syncthreads();

    // hoist row i of X into registers (constant across Horner iters)
    float2 Xr[16];
    #pragma unroll
    for (int t = 0; t < 16; ++t) Xr[t] = X[i * 16 + t];

    float2* cur = P0;
    float2* nxt = P1;
    // Horner: P = I + X*P/k for k = N-1 .. 1
    for (int k = TAYLOR_N - 1; k >= 1; --k) {
        float accr = 0.f, acci = 0.f;
        #pragma unroll
        for (int t = 0; t < 16; ++t) {
            float2 a = Xr[t];
            float2 b = cur[t * 16 + j];
            accr += a.x * b.x - a.y * b.y;
            acci += a.x * b.y + a.y * b.x;
        }
        float inv = 1.f / (float)k;
        float2 np = make_float2(accr * inv + ((i == j) ? 1.f : 0.f), acci * inv);
        __syncthreads();
        nxt[tid] = np;
        __syncthreads();
        float2* tmp = cur; cur = nxt; nxt = tmp;
    }
    // squarings
    for (int sq = 0; sq < sexp; ++sq) {
        float accr = 0.f, acci = 0.f;
        #pragma unroll
        for (int t = 0; t < 16; ++t) {
            float2 a = cur[i * 16 + t];
            float2 b = cur[t * 16 + j];
            accr += a.x * b.x - a.y * b.y;
            acci += a.x * b.y + a.y * b.x;
        }
        __syncthreads();
        nxt[tid] = make_float2(accr, acci);
        __syncthreads();
        float2* tmp = cur; cur = nxt; nxt = tmp;
    }
    // E[i][j] = U[i][j]; store W'[j][i] = U[i][j]*(-i)^popc(i)
    float2 e = cur[tid];
    int pc = __popc(i) & 3;
    float2 o;
    if (pc == 0)      o = make_float2( e.x,  e.y);
    else if (pc == 1) o = make_float2( e.y, -e.x);
    else if (pc == 2) o = make_float2(-e.x, -e.y);
    else              o = make_float2(-e.y,  e.x);
    wp[(bid * 16 + j) * 16 + i] = o;
}

// Fast acos: A&S 4.4.45, |abs err| <= 6.8e-5 over [-1,1]
__device__ __forceinline__ float acos_fast(float t) {
    float ax = fabsf(t);
    float p = fmaf(ax, -0.0187293f, 0.0742610f);
    p = fmaf(ax, p, -0.2121144f);
    p = fmaf(ax, p, 1.5707288f);
    float f = sqrtf(1.0f - ax) * p;
    return (t >= 0.f) ? f : (3.14159265358979f - f);
}

// ---------------- Kernel 2: main compute ------------------------------------
// grid = 8(d) * 2(chalf) * 128(mb) blocks, 256 threads. (d, chalf) from
// blockIdx -> uniform. W' matrices for this block's (c0,c1,d) are staged in
// LDS (4 KB) and read back as ds_read_b128 broadcasts (all lanes same addr,
// conflict-free) -> removes the s_load scalar-cache stall that capped matvec.
// Two blocks contribute per output element via fp32 atomicAdd (2 commutative
// contributions -> deterministic).
__global__ __launch_bounds__(256) void qconv_kernel(const float* __restrict__ x,
                                                    const float2* __restrict__ wp,
                                                    float* __restrict__ out) {
    __shared__ float4 Wlds[256];      // [cc][j][8 float4] : 2 * 2KB

    const int bidx = blockIdx.x;
    const int d = bidx >> 8;          // uniform per block
    const int rest = bidx & 255;
    const int chalf = rest >> 7;      // uniform per block
    const int mb = rest & 127;
    const int tid = threadIdx.x;

    // cooperative stage: c = 2*chalf + (tid>>7), 128 float4 per matrix
    {
        const float4* wp4 = (const float4*)wp;
        const int cc = tid >> 7;
        const int off = tid & 127;
        Wlds[tid] = wp4[((((chalf << 1) + cc) << 3) + d) * 128 + off];
    }
    __syncthreads();

    const int m = mb * 256 + tid;
    const int b = m >> 10;
    const int rem = m & 1023;
    const int ix = rem >> 5;
    const int iy = rem & 31;

    float outacc0 = 0.f, outacc1 = 0.f, outacc2 = 0.f, outacc3 = 0.f;

    #pragma unroll
    for (int cc = 0; cc < 2; ++cc) {
        const int c = chalf * 2 + cc;
        const float* xc = x + (((b << 2) + c) * 64 + 2 * ix) * 64 + 2 * iy;
        float2 p0 = *(const float2*)xc;          // theta0, theta1 (kh=0)
        float2 p1 = *(const float2*)(xc + 64);   // theta2, theta3 (kh=1)

        float sn0, cs0, sn1, cs1, sn2, cs2, sn3, cs3;
        __sincosf(p0.x * 0.5f, &sn0, &cs0);
        __sincosf(p0.y * 0.5f, &sn1, &cs1);
        __sincosf(p1.x * 0.5f, &sn2, &cs2);
        __sincosf(p1.y * 0.5f, &sn3, &cs3);

        // r[k], k = b0*8+b1*4+b2*2+b3 (wire0 = MSB), factor = bit? sin : cos
        float r4[4];
        r4[0] = cs0 * cs1; r4[1] = cs0 * sn1; r4[2] = sn0 * cs1; r4[3] = sn0 * sn1;
        float r8[8];
        #pragma unroll
        for (int t = 0; t < 4; ++t) { r8[2 * t] = r4[t] * cs2; r8[2 * t + 1] = r4[t] * sn2; }
        float r[16];
        #pragma unroll
        for (int t = 0; t < 8; ++t) { r[2 * t] = r8[t] * cs3; r[2 * t + 1] = r8[t] * sn3; }

        // matvec: y_j = sum_k W'[j][k] * r[k]  (W' complex, r real), W' in LDS
        const float4* __restrict__ wmat = &Wlds[cc << 7];
        float q[16];
        #pragma unroll
        for (int jj = 0; jj < 16; ++jj) {
            const float4* wr4 = wmat + (jj << 3);
            float yr = 0.f, yi = 0.f;
            #pragma unroll
            for (int kk = 0; kk < 8; ++kk) {
                float4 wv = wr4[kk];
                yr = fmaf(wv.x, r[2 * kk], yr);
                yi = fmaf(wv.y, r[2 * kk], yi);
                yr = fmaf(wv.z, r[2 * kk + 1], yr);
                yi = fmaf(wv.w, r[2 * kk + 1], yi);
            }
            q[jj] = yr * yr + yi * yi;
        }

        // marginals via partial-sum butterfly
        float s1[8], t3 = 0.f;
        #pragma unroll
        for (int a = 0; a < 8; ++a) {
            s1[a] = q[2 * a] + q[2 * a + 1];
            t3 += q[2 * a] - q[2 * a + 1];
        }
        float s2[4], t2 = 0.f;
        #pragma unroll
        for (int a = 0; a < 4; ++a) {
            s2[a] = s1[2 * a] + s1[2 * a + 1];
            t2 += s1[2 * a] - s1[2 * a + 1];
        }
        float s30 = s2[0] + s2[1], s31 = s2[2] + s2[3];
        float t1 = (s2[0] - s2[1]) + (s2[2] - s2[3]);
        float t0 = s30 - s31;

        outacc0 += acos_fast(fminf(fmaxf(t0, -1.f), 1.f));
        outacc1 += acos_fast(fminf(fmaxf(t1, -1.f), 1.f));
        outacc2 += acos_fast(fminf(fmaxf(t2, -1.f), 1.f));
        outacc3 += acos_fast(fminf(fmaxf(t3, -1.f), 1.f));
    }

    // out[b][d*4+w][ix][iy], channel stride 1024; two blocks (chalf 0/1) add here
    float* ob = out + (((b * 32) + (d << 2)) * 32 + ix) * 32 + iy;
    unsafeAtomicAdd(ob,        outacc0);
    unsafeAtomicAdd(ob + 1024, outacc1);
    unsafeAtomicAdd(ob + 2048, outacc2);
    unsafeAtomicAdd(ob + 3072, outacc3);
}

extern "C" void kernel_launch(void* const* d_in, const int* in_sizes, int n_in,
                              void* d_out, int out_size, void* d_ws, size_t ws_size,
                              hipStream_t stream) {
    const float* x = (const float*)d_in[0];
    const float* params = (const float*)d_in[1];
    float* out = (float*)d_out;
    float2* wp = (float2*)d_ws;   // 32 * 256 * 8 bytes = 64 KiB

    zero_kernel<<<1024, 256, 0, stream>>>((float4*)out);   // 4 MB, one pass
    expm_kernel<<<NMAT, 256, 0, stream>>>(params, wp);
    qconv_kernel<<<8 * 2 * 128, 256, 0, stream>>>(x, wp, out);
}

// Round 7
// 58.996 us; speedup vs baseline: 1.0217x; 1.0217x over previous
//
#include <hip/hip_runtime.h>
#include <math.h>

// QConv2d: x (32,4,64,64) f32, params (4,8,16,16) f32 -> out (32,32,32,32) f32
// B=32 C=4 H=W=64, KH=KW=2 stride 2 -> px=py=32, NW=4, DIM=16, D=8, M=32768

#define TAYLOR_N 9

// ---------------- Kernel 1: zero the output (all 1024 blocks) + expm (blocks<32)
// W'[c*8+d][j][i] = expm(SH)[i][j] * (-i)^popc(i)
__global__ __launch_bounds__(256) void prep_kernel(const float* __restrict__ params,
                                                   float2* __restrict__ wp,
                                                   float4* __restrict__ outz) {
    // zero a 4KB slice of out (1024 blocks x 256 threads x 16B = 4MB)
    outz[blockIdx.x * 256 + threadIdx.x] = make_float4(0.f, 0.f, 0.f, 0.f);
    if (blockIdx.x >= 32) return;

    __shared__ float2 X[256];
    __shared__ float2 P0[256];
    __shared__ float2 P1[256];
    __shared__ float red[256];
    __shared__ float srow[16];
    __shared__ int ssexp;

    const int bid = blockIdx.x;      // c*8 + d
    const int tid = threadIdx.x;
    const int i = tid >> 4, j = tid & 15;

    const float* pm = params + bid * 256;
    float pij = pm[i * 16 + j];
    float pji = pm[j * 16 + i];
    float ar = pij - pji;   // asym -> real part of SH
    float ai = pij + pji;   // sym  -> imag part of SH
    red[tid] = fabsf(ar) + fabsf(ai);
    __syncthreads();
    if (j == 0) {
        float s = 0.f;
        for (int t = 0; t < 16; ++t) s += red[i * 16 + t];
        srow[i] = s;
    }
    __syncthreads();
    if (tid == 0) {
        float mx = 0.f;
        for (int t = 0; t < 16; ++t) mx = fmaxf(mx, srow[t]);
        int se = 0;
        while (mx > 0.5f && se < 40) { mx *= 0.5f; se++; }
        ssexp = se;
    }
    __syncthreads();
    const int sexp = ssexp;
    const float scale = exp2f((float)(-sexp));
    const float xr = ar * scale, xi = ai * scale;
    X[tid] = make_float2(xr, xi);
    float2 p = make_float2(xr / TAYLOR_N + ((i == j) ? 1.f : 0.f), xi / TAYLOR_N);
    P0[tid] = p;
    __syncthreads();

    float2 Xr[16];
    #pragma unroll
    for (int t = 0; t < 16; ++t) Xr[t] = X[i * 16 + t];

    float2* cur = P0;
    float2* nxt = P1;
    for (int k = TAYLOR_N - 1; k >= 1; --k) {
        float accr = 0.f, acci = 0.f;
        #pragma unroll
        for (int t = 0; t < 16; ++t) {
            float2 a = Xr[t];
            float2 bb = cur[t * 16 + j];
            accr += a.x * bb.x - a.y * bb.y;
            acci += a.x * bb.y + a.y * bb.x;
        }
        float inv = 1.f / (float)k;
        float2 np = make_float2(accr * inv + ((i == j) ? 1.f : 0.f), acci * inv);
        __syncthreads();
        nxt[tid] = np;
        __syncthreads();
        float2* tmp = cur; cur = nxt; nxt = tmp;
    }
    for (int sq = 0; sq < sexp; ++sq) {
        float accr = 0.f, acci = 0.f;
        #pragma unroll
        for (int t = 0; t < 16; ++t) {
            float2 a = cur[i * 16 + t];
            float2 bb = cur[t * 16 + j];
            accr += a.x * bb.x - a.y * bb.y;
            acci += a.x * bb.y + a.y * bb.x;
        }
        __syncthreads();
        nxt[tid] = make_float2(accr, acci);
        __syncthreads();
        float2* tmp = cur; cur = nxt; nxt = tmp;
    }
    float2 e = cur[tid];
    int pc = __popc(i) & 3;
    float2 o;
    if (pc == 0)      o = make_float2( e.x,  e.y);
    else if (pc == 1) o = make_float2( e.y, -e.x);
    else if (pc == 2) o = make_float2(-e.x, -e.y);
    else              o = make_float2(-e.y,  e.x);
    wp[(bid * 16 + j) * 16 + i] = o;
}

// Fast acos: A&S 4.4.45, |abs err| <= 6.8e-5 over [-1,1]
__device__ __forceinline__ float acos_fast(float t) {
    float ax = fabsf(t);
    float p = fmaf(ax, -0.0187293f, 0.0742610f);
    p = fmaf(ax, p, -0.2121144f);
    p = fmaf(ax, p, 1.5707288f);
    float f = sqrtf(1.0f - ax) * p;
    return (t >= 0.f) ? f : (3.14159265358979f - f);
}

// ---------------- Kernel 2: main compute ------------------------------------
// G=4 sites per thread. grid = 8(d) * 2(chalf) * 32(b) blocks, 256 threads.
// (d, chalf, b) from blockIdx -> W' pointer provably uniform -> rows come via
// s_load (scalar cache pipe; not DS, not VMEM). Each row load feeds 4 sites
// (128 FMAs ~ 300 cyc) -> scalar-load latency fully hidden (R1's stall) and
// DS pipe unused (R6's 41us bottleneck). Two blocks (chalf 0/1) add per output
// element via fp32 atomicAdd: 2 commutative contributions -> deterministic.
__global__ __launch_bounds__(256) void qconv_kernel(const float* __restrict__ x,
                                                    const float2* __restrict__ wp,
                                                    float* __restrict__ out) {
    const int bidx = blockIdx.x;          // (d*2 + chalf)*32 + b
    const int d = bidx >> 6;              // uniform
    const int chalf = (bidx >> 5) & 1;    // uniform
    const int b = bidx & 31;              // uniform
    const int tid = threadIdx.x;
    const int ix = tid >> 3;              // 0..31
    const int iy0 = (tid & 7) << 2;       // 0,4,..,28 ; sites iy0..iy0+3

    float outsum[4][4];                   // [site][w]
    #pragma unroll
    for (int s = 0; s < 4; ++s)
        #pragma unroll
        for (int w = 0; w < 4; ++w) outsum[s][w] = 0.f;

    #pragma unroll 1
    for (int cc = 0; cc < 2; ++cc) {
        const int c = chalf * 2 + cc;
        const float* xr = x + (((b << 2) + c) * 64 + 2 * ix) * 64 + 2 * iy0;
        float4 a0 = *(const float4*)(xr);        // row0 cols 2iy0..+3
        float4 a1 = *(const float4*)(xr + 4);    // row0 cols +4..+7
        float4 b0 = *(const float4*)(xr + 64);   // row1
        float4 b1 = *(const float4*)(xr + 68);

        // site s angles: {row0[2s], row0[2s+1], row1[2s], row1[2s+1]}
        const float th[4][4] = {
            {a0.x, a0.y, b0.x, b0.y},
            {a0.z, a0.w, b0.z, b0.w},
            {a1.x, a1.y, b1.x, b1.y},
            {a1.z, a1.w, b1.z, b1.w},
        };

        float r[4][16];
        #pragma unroll
        for (int s = 0; s < 4; ++s) {
            float sn0, cs0, sn1, cs1, sn2, cs2, sn3, cs3;
            __sincosf(th[s][0] * 0.5f, &sn0, &cs0);
            __sincosf(th[s][1] * 0.5f, &sn1, &cs1);
            __sincosf(th[s][2] * 0.5f, &sn2, &cs2);
            __sincosf(th[s][3] * 0.5f, &sn3, &cs3);
            float r4a[4] = {cs0 * cs1, cs0 * sn1, sn0 * cs1, sn0 * sn1};
            float r8a[8];
            #pragma unroll
            for (int t = 0; t < 4; ++t) { r8a[2 * t] = r4a[t] * cs2; r8a[2 * t + 1] = r4a[t] * sn2; }
            #pragma unroll
            for (int t = 0; t < 8; ++t) { r[s][2 * t] = r8a[t] * cs3; r[s][2 * t + 1] = r8a[t] * sn3; }
        }

        const float2* __restrict__ wrow = wp + ((c << 3) + d) * 256;  // uniform
        float tq[4][4];                   // per-c Walsh sums [site][w]
        #pragma unroll
        for (int s = 0; s < 4; ++s)
            #pragma unroll
            for (int w = 0; w < 4; ++w) tq[s][w] = 0.f;

        #pragma unroll
        for (int jj = 0; jj < 16; ++jj) {
            const float4* wr4 = (const float4*)(wrow + jj * 16);
            #pragma unroll
            for (int s = 0; s < 4; ++s) {
                float yr = 0.f, yi = 0.f;
                #pragma unroll
                for (int kk = 0; kk < 8; ++kk) {
                    float4 wv = wr4[kk];   // CSE'd across s (uniform s_load)
                    yr = fmaf(wv.x, r[s][2 * kk], yr);
                    yi = fmaf(wv.y, r[s][2 * kk], yi);
                    yr = fmaf(wv.z, r[s][2 * kk + 1], yr);
                    yi = fmaf(wv.w, r[s][2 * kk + 1], yi);
                }
                float q = fmaf(yr, yr, yi * yi);
                // w uses bit (3-w) of jj: add if 0, sub if 1 (compile-time)
                if ((jj >> 3) & 1) tq[s][0] -= q; else tq[s][0] += q;
                if ((jj >> 2) & 1) tq[s][1] -= q; else tq[s][1] += q;
                if ((jj >> 1) & 1) tq[s][2] -= q; else tq[s][2] += q;
                if ((jj >> 0) & 1) tq[s][3] -= q; else tq[s][3] += q;
            }
        }

        #pragma unroll
        for (int s = 0; s < 4; ++s)
            #pragma unroll
            for (int w = 0; w < 4; ++w)
                outsum[s][w] += acos_fast(fminf(fmaxf(tq[s][w], -1.f), 1.f));
    }

    // out[b][d*4+w][ix][iy0+s]; two blocks (chalf 0/1) add here
    float* ob = out + (((b * 32) + (d << 2)) * 32 + ix) * 32 + iy0;
    #pragma unroll
    for (int w = 0; w < 4; ++w)
        #pragma unroll
        for (int s = 0; s < 4; ++s)
            unsafeAtomicAdd(ob + w * 1024 + s, outsum[s][w]);
}

extern "C" void kernel_launch(void* const* d_in, const int* in_sizes, int n_in,
                              void* d_out, int out_size, void* d_ws, size_t ws_size,
                              hipStream_t stream) {
    const float* x = (const float*)d_in[0];
    const float* params = (const float*)d_in[1];
    float* out = (float*)d_out;
    float2* wp = (float2*)d_ws;   // 32 * 256 * 8 bytes = 64 KiB

    prep_kernel<<<1024, 256, 0, stream>>>(params, wp, (float4*)out);
    qconv_kernel<<<8 * 2 * 32, 256, 0, stream>>>(x, wp, out);
}

// Round 8
// 58.989 us; speedup vs baseline: 1.0218x; 1.0001x over previous
//
#include <hip/hip_runtime.h>
#include <math.h>

// QConv2d: x (32,4,64,64) f32, params (4,8,16,16) f32 -> out (32,32,32,32) f32
// B=32 C=4 H=W=64, KH=KW=2 stride 2 -> px=py=32, NW=4, DIM=16, D=8, M=32768

#define TAYLOR_N 9

// ---------------- Kernel 1: zero the output (all 1024 blocks) + expm (blocks<32)
// W'[c*8+d][j][i] = expm(SH)[i][j] * (-i)^popc(i)
__global__ __launch_bounds__(256) void prep_kernel(const float* __restrict__ params,
                                                   float2* __restrict__ wp,
                                                   float4* __restrict__ outz) {
    // zero a 4KB slice of out (1024 blocks x 256 threads x 16B = 4MB)
    outz[blockIdx.x * 256 + threadIdx.x] = make_float4(0.f, 0.f, 0.f, 0.f);
    if (blockIdx.x >= 32) return;

    __shared__ float2 X[256];
    __shared__ float2 P0[256];
    __shared__ float2 P1[256];
    __shared__ float red[256];
    __shared__ float srow[16];
    __shared__ int ssexp;

    const int bid = blockIdx.x;      // c*8 + d
    const int tid = threadIdx.x;
    const int i = tid >> 4, j = tid & 15;

    const float* pm = params + bid * 256;
    float pij = pm[i * 16 + j];
    float pji = pm[j * 16 + i];
    float ar = pij - pji;   // asym -> real part of SH
    float ai = pij + pji;   // sym  -> imag part of SH
    red[tid] = fabsf(ar) + fabsf(ai);
    __syncthreads();
    if (j == 0) {
        float s = 0.f;
        for (int t = 0; t < 16; ++t) s += red[i * 16 + t];
        srow[i] = s;
    }
    __syncthreads();
    if (tid == 0) {
        float mx = 0.f;
        for (int t = 0; t < 16; ++t) mx = fmaxf(mx, srow[t]);
        int se = 0;
        while (mx > 0.5f && se < 40) { mx *= 0.5f; se++; }
        ssexp = se;
    }
    __syncthreads();
    const int sexp = ssexp;
    const float scale = exp2f((float)(-sexp));
    const float xr = ar * scale, xi = ai * scale;
    X[tid] = make_float2(xr, xi);
    float2 p = make_float2(xr / TAYLOR_N + ((i == j) ? 1.f : 0.f), xi / TAYLOR_N);
    P0[tid] = p;
    __syncthreads();

    float2 Xr[16];
    #pragma unroll
    for (int t = 0; t < 16; ++t) Xr[t] = X[i * 16 + t];

    float2* cur = P0;
    float2* nxt = P1;
    for (int k = TAYLOR_N - 1; k >= 1; --k) {
        float accr = 0.f, acci = 0.f;
        #pragma unroll
        for (int t = 0; t < 16; ++t) {
            float2 a = Xr[t];
            float2 bb = cur[t * 16 + j];
            accr += a.x * bb.x - a.y * bb.y;
            acci += a.x * bb.y + a.y * bb.x;
        }
        float inv = 1.f / (float)k;
        float2 np = make_float2(accr * inv + ((i == j) ? 1.f : 0.f), acci * inv);
        __syncthreads();
        nxt[tid] = np;
        __syncthreads();
        float2* tmp = cur; cur = nxt; nxt = tmp;
    }
    for (int sq = 0; sq < sexp; ++sq) {
        float accr = 0.f, acci = 0.f;
        #pragma unroll
        for (int t = 0; t < 16; ++t) {
            float2 a = cur[i * 16 + t];
            float2 bb = cur[t * 16 + j];
            accr += a.x * bb.x - a.y * bb.y;
            acci += a.x * bb.y + a.y * bb.x;
        }
        __syncthreads();
        nxt[tid] = make_float2(accr, acci);
        __syncthreads();
        float2* tmp = cur; cur = nxt; nxt = tmp;
    }
    float2 e = cur[tid];
    int pc = __popc(i) & 3;
    float2 o;
    if (pc == 0)      o = make_float2( e.x,  e.y);
    else if (pc == 1) o = make_float2( e.y, -e.x);
    else if (pc == 2) o = make_float2(-e.x, -e.y);
    else              o = make_float2(-e.y,  e.x);
    wp[(bid * 16 + j) * 16 + i] = o;
}

// Fast acos: A&S 4.4.45, |abs err| <= 6.8e-5 over [-1,1]
__device__ __forceinline__ float acos_fast(float t) {
    float ax = fabsf(t);
    float p = fmaf(ax, -0.0187293f, 0.0742610f);
    p = fmaf(ax, p, -0.2121144f);
    p = fmaf(ax, p, 1.5707288f);
    float f = sqrtf(1.0f - ax) * p;
    return (t >= 0.f) ? f : (3.14159265358979f - f);
}

// ---------------- Kernel 2: main compute ------------------------------------
// G=4 sites per thread. grid = 8(d) * 2(chalf) * 32(b) blocks, 256 threads.
// (d, chalf, b) from blockIdx -> W' pointer provably uniform -> rows via
// s_load; each row feeds 4 sites (128 FMAs) so scalar latency is hidden.
// __launch_bounds__(256, 1): R7's failure was the backend capping VGPR at 60
// (occupancy heuristic) and spilling r[4][16] to scratch (WRITE_SIZE showed
// 24 MB of scratch writes). Min-1-wave/EU raises the cap to 512 VGPR; grid is
// only 2 waves/SIMD anyway. Two blocks (chalf 0/1) add per output element via
// fp32 atomicAdd: 2 commutative contributions -> deterministic.
__global__ __launch_bounds__(256, 1) void qconv_kernel(const float* __restrict__ x,
                                                       const float2* __restrict__ wp,
                                                       float* __restrict__ out) {
    const int bidx = blockIdx.x;          // (d*2 + chalf)*32 + b
    const int d = bidx >> 6;              // uniform
    const int chalf = (bidx >> 5) & 1;    // uniform
    const int b = bidx & 31;              // uniform
    const int tid = threadIdx.x;
    const int ix = tid >> 3;              // 0..31
    const int iy0 = (tid & 7) << 2;       // 0,4,..,28 ; sites iy0..iy0+3

    float outsum[4][4];                   // [site][w]
    #pragma unroll
    for (int s = 0; s < 4; ++s)
        #pragma unroll
        for (int w = 0; w < 4; ++w) outsum[s][w] = 0.f;

    #pragma unroll 1
    for (int cc = 0; cc < 2; ++cc) {
        const int c = chalf * 2 + cc;
        const float* xr = x + (((b << 2) + c) * 64 + 2 * ix) * 64 + 2 * iy0;
        float4 a0 = *(const float4*)(xr);        // row0 cols 2iy0..+3
        float4 a1 = *(const float4*)(xr + 4);    // row0 cols +4..+7
        float4 b0 = *(const float4*)(xr + 64);   // row1
        float4 b1 = *(const float4*)(xr + 68);

        // site s angles: {row0[2s], row0[2s+1], row1[2s], row1[2s+1]}
        float r[4][16];
        #pragma unroll
        for (int s = 0; s < 4; ++s) {
            float t0 = (s == 0) ? a0.x : (s == 1) ? a0.z : (s == 2) ? a1.x : a1.z;
            float t1 = (s == 0) ? a0.y : (s == 1) ? a0.w : (s == 2) ? a1.y : a1.w;
            float t2 = (s == 0) ? b0.x : (s == 1) ? b0.z : (s == 2) ? b1.x : b1.z;
            float t3 = (s == 0) ? b0.y : (s == 1) ? b0.w : (s == 2) ? b1.y : b1.w;
            float sn0, cs0, sn1, cs1, sn2, cs2, sn3, cs3;
            __sincosf(t0 * 0.5f, &sn0, &cs0);
            __sincosf(t1 * 0.5f, &sn1, &cs1);
            __sincosf(t2 * 0.5f, &sn2, &cs2);
            __sincosf(t3 * 0.5f, &sn3, &cs3);
            float r4a[4] = {cs0 * cs1, cs0 * sn1, sn0 * cs1, sn0 * sn1};
            float r8a[8];
            #pragma unroll
            for (int t = 0; t < 4; ++t) { r8a[2 * t] = r4a[t] * cs2; r8a[2 * t + 1] = r4a[t] * sn2; }
            #pragma unroll
            for (int t = 0; t < 8; ++t) { r[s][2 * t] = r8a[t] * cs3; r[s][2 * t + 1] = r8a[t] * sn3; }
        }

        const float2* __restrict__ wrow = wp + ((c << 3) + d) * 256;  // uniform
        float tq[4][4];                   // per-c Walsh sums [site][w]
        #pragma unroll
        for (int s = 0; s < 4; ++s)
            #pragma unroll
            for (int w = 0; w < 4; ++w) tq[s][w] = 0.f;

        #pragma unroll
        for (int jj = 0; jj < 16; ++jj) {
            const float4* wr4 = (const float4*)(wrow + jj * 16);
            #pragma unroll
            for (int s = 0; s < 4; ++s) {
                float yr = 0.f, yi = 0.f;
                #pragma unroll
                for (int kk = 0; kk < 8; ++kk) {
                    float4 wv = wr4[kk];   // CSE'd across s (uniform s_load)
                    yr = fmaf(wv.x, r[s][2 * kk], yr);
                    yi = fmaf(wv.y, r[s][2 * kk], yi);
                    yr = fmaf(wv.z, r[s][2 * kk + 1], yr);
                    yi = fmaf(wv.w, r[s][2 * kk + 1], yi);
                }
                float q = fmaf(yr, yr, yi * yi);
                // w uses bit (3-w) of jj: add if 0, sub if 1 (compile-time)
                if ((jj >> 3) & 1) tq[s][0] -= q; else tq[s][0] += q;
                if ((jj >> 2) & 1) tq[s][1] -= q; else tq[s][1] += q;
                if ((jj >> 1) & 1) tq[s][2] -= q; else tq[s][2] += q;
                if ((jj >> 0) & 1) tq[s][3] -= q; else tq[s][3] += q;
            }
        }

        #pragma unroll
        for (int s = 0; s < 4; ++s)
            #pragma unroll
            for (int w = 0; w < 4; ++w)
                outsum[s][w] += acos_fast(fminf(fmaxf(tq[s][w], -1.f), 1.f));
    }

    // out[b][d*4+w][ix][iy0+s]; two blocks (chalf 0/1) add here
    float* ob = out + (((b * 32) + (d << 2)) * 32 + ix) * 32 + iy0;
    #pragma unroll
    for (int w = 0; w < 4; ++w)
        #pragma unroll
        for (int s = 0; s < 4; ++s)
            unsafeAtomicAdd(ob + w * 1024 + s, outsum[s][w]);
}

extern "C" void kernel_launch(void* const* d_in, const int* in_sizes, int n_in,
                              void* d_out, int out_size, void* d_ws, size_t ws_size,
                              hipStream_t stream) {
    const float* x = (const float*)d_in[0];
    const float* params = (const float*)d_in[1];
    float* out = (float*)d_out;
    float2* wp = (float2*)d_ws;   // 32 * 256 * 8 bytes = 64 KiB

    prep_kernel<<<1024, 256, 0, stream>>>(params, wp, (float4*)out);
    qconv_kernel<<<8 * 2 * 32, 256, 0, stream>>>(x, wp, out);
}

// Round 9
// 39.290 us; speedup vs baseline: 1.5342x; 1.5014x over previous
//
#include <hip/hip_runtime.h>
#include <math.h>

// QConv2d: x (32,4,64,64) f32, params (4,8,16,16) f32 -> out (32,32,32,32) f32
// B=32 C=4 H=W=64, KH=KW=2 stride 2 -> px=py=32, NW=4, DIM=16, D=8, M=32768

#define TAYLOR_N 9

// ---------------- Kernel 1: zero the output (all 1024 blocks) + expm (blocks<32)
// W'[c*8+d][j][i] = expm(SH)[i][j] * (-i)^popc(i)
__global__ __launch_bounds__(256) void prep_kernel(const float* __restrict__ params,
                                                   float2* __restrict__ wp,
                                                   float4* __restrict__ outz) {
    outz[blockIdx.x * 256 + threadIdx.x] = make_float4(0.f, 0.f, 0.f, 0.f);
    if (blockIdx.x >= 32) return;

    __shared__ float2 X[256];
    __shared__ float2 P0[256];
    __shared__ float2 P1[256];
    __shared__ float red[256];
    __shared__ float srow[16];
    __shared__ int ssexp;

    const int bid = blockIdx.x;      // c*8 + d
    const int tid = threadIdx.x;
    const int i = tid >> 4, j = tid & 15;

    const float* pm = params + bid * 256;
    float pij = pm[i * 16 + j];
    float pji = pm[j * 16 + i];
    float ar = pij - pji;   // asym -> real part of SH
    float ai = pij + pji;   // sym  -> imag part of SH
    red[tid] = fabsf(ar) + fabsf(ai);
    __syncthreads();
    if (j == 0) {
        float s = 0.f;
        for (int t = 0; t < 16; ++t) s += red[i * 16 + t];
        srow[i] = s;
    }
    __syncthreads();
    if (tid == 0) {
        float mx = 0.f;
        for (int t = 0; t < 16; ++t) mx = fmaxf(mx, srow[t]);
        int se = 0;
        while (mx > 0.5f && se < 40) { mx *= 0.5f; se++; }
        ssexp = se;
    }
    __syncthreads();
    const int sexp = ssexp;
    const float scale = exp2f((float)(-sexp));
    const float xr = ar * scale, xi = ai * scale;
    X[tid] = make_float2(xr, xi);
    float2 p = make_float2(xr / TAYLOR_N + ((i == j) ? 1.f : 0.f), xi / TAYLOR_N);
    P0[tid] = p;
    __syncthreads();

    float2 Xr[16];
    #pragma unroll
    for (int t = 0; t < 16; ++t) Xr[t] = X[i * 16 + t];

    float2* cur = P0;
    float2* nxt = P1;
    for (int k = TAYLOR_N - 1; k >= 1; --k) {
        float accr = 0.f, acci = 0.f;
        #pragma unroll
        for (int t = 0; t < 16; ++t) {
            float2 a = Xr[t];
            float2 bb = cur[t * 16 + j];
            accr += a.x * bb.x - a.y * bb.y;
            acci += a.x * bb.y + a.y * bb.x;
        }
        float inv = 1.f / (float)k;
        float2 np = make_float2(accr * inv + ((i == j) ? 1.f : 0.f), acci * inv);
        __syncthreads();
        nxt[tid] = np;
        __syncthreads();
        float2* tmp = cur; cur = nxt; nxt = tmp;
    }
    for (int sq = 0; sq < sexp; ++sq) {
        float accr = 0.f, acci = 0.f;
        #pragma unroll
        for (int t = 0; t < 16; ++t) {
            float2 a = cur[i * 16 + t];
            float2 bb = cur[t * 16 + j];
            accr += a.x * bb.x - a.y * bb.y;
            acci += a.x * bb.y + a.y * bb.x;
        }
        __syncthreads();
        nxt[tid] = make_float2(accr, acci);
        __syncthreads();
        float2* tmp = cur; cur = nxt; nxt = tmp;
    }
    float2 e = cur[tid];
    int pc = __popc(i) & 3;
    float2 o;
    if (pc == 0)      o = make_float2( e.x,  e.y);
    else if (pc == 1) o = make_float2( e.y, -e.x);
    else if (pc == 2) o = make_float2(-e.x, -e.y);
    else              o = make_float2(-e.y,  e.x);
    wp[(bid * 16 + j) * 16 + i] = o;
}

// Fast acos: A&S 4.4.45, |abs err| <= 6.8e-5 over [-1,1]
__device__ __forceinline__ float acos_fast(float t) {
    float ax = fabsf(t);
    float p = fmaf(ax, -0.0187293f, 0.0742610f);
    p = fmaf(ax, p, -0.2121144f);
    p = fmaf(ax, p, 1.5707288f);
    float f = sqrtf(1.0f - ax) * p;
    return (t >= 0.f) ? f : (3.14159265358979f - f);
}

// build r[16] for one site from 4 angles (wire0 = MSB of k)
#define BUILD_R(rr, T0, T1, T2, T3) do {                                   \
    float sn0, cs0, sn1, cs1, sn2, cs2, sn3, cs3;                          \
    __sincosf((T0) * 0.5f, &sn0, &cs0);                                    \
    __sincosf((T1) * 0.5f, &sn1, &cs1);                                    \
    __sincosf((T2) * 0.5f, &sn2, &cs2);                                    \
    __sincosf((T3) * 0.5f, &sn3, &cs3);                                    \
    float p00 = cs0 * cs1, p01 = cs0 * sn1, p10 = sn0 * cs1, p11 = sn0 * sn1; \
    float e0 = p00 * cs2, e1 = p00 * sn2, e2 = p01 * cs2, e3 = p01 * sn2;  \
    float e4 = p10 * cs2, e5 = p10 * sn2, e6 = p11 * cs2, e7 = p11 * sn2;  \
    rr[0]  = e0 * cs3; rr[1]  = e0 * sn3; rr[2]  = e1 * cs3; rr[3]  = e1 * sn3; \
    rr[4]  = e2 * cs3; rr[5]  = e2 * sn3; rr[6]  = e3 * cs3; rr[7]  = e3 * sn3; \
    rr[8]  = e4 * cs3; rr[9]  = e4 * sn3; rr[10] = e5 * cs3; rr[11] = e5 * sn3; \
    rr[12] = e6 * cs3; rr[13] = e6 * sn3; rr[14] = e7 * cs3; rr[15] = e7 * sn3; \
} while (0)

#define SITE_FMA(rr, YR, YI)                                               \
    YR = fmaf(wv.x, rr[2 * kk], YR); YI = fmaf(wv.y, rr[2 * kk], YI);      \
    YR = fmaf(wv.z, rr[2 * kk + 1], YR); YI = fmaf(wv.w, rr[2 * kk + 1], YI);

// ---------------- Kernel 2: main compute ------------------------------------
// G=4 sites/thread. grid = 8(d)*2(chalf)*32(b) blocks, 256 threads.
// W' (both c of this chalf) staged in LDS (4KB), rows read as ds_read_b128
// broadcast (same addr all lanes = conflict-free), each row feeds 4 sites ->
// DS cycles/CU ~ 10us, below the ~18us VALU side (R6 was DS-bound at G=1).
// amdgpu_waves_per_eu(2,4): R7/R8's allocator targeted 8 waves/EU (60 VGPR)
// and spilled r[4][16]; grid only provides 2 waves/SIMD, so target that.
// Epilogue: partials transposed through LDS (sp = 4*tid+s identity) so the
// 2-way deterministic atomics hit lane-consecutive dwords (R7's stride-4
// lanes caused 4x HBM RMW amplification: 32MB vs 8MB).
__global__ __launch_bounds__(256)
__attribute__((amdgpu_waves_per_eu(2, 4)))
void qconv_kernel(const float* __restrict__ x,
                  const float2* __restrict__ wp,
                  float* __restrict__ out) {
    __shared__ float4 Wlds[2][16][8];     // [cc][row j][8 float4] = 4 KB
    __shared__ float  olds[4096];         // [w][sp] partial transpose, 16 KB

    const int bidx = blockIdx.x;          // (d*2 + chalf)*32 + b
    const int d = bidx >> 6;              // uniform
    const int chalf = (bidx >> 5) & 1;    // uniform
    const int b = bidx & 31;              // uniform
    const int tid = threadIdx.x;
    const int ix = tid >> 3;              // 0..31
    const int iy0 = (tid & 7) << 2;       // 0,4,..,28 ; sites iy0..iy0+3

    // stage both W' matrices for (chalf, d)
    {
        const float4* wp4 = (const float4*)wp;
        const int cc = tid >> 7;
        const int off = tid & 127;
        ((float4*)Wlds)[tid] = wp4[((((chalf << 1) + cc) << 3) + d) * 128 + off];
    }
    __syncthreads();

    float outsum[4][4];                   // [site][w]
    #pragma unroll
    for (int s = 0; s < 4; ++s)
        #pragma unroll
        for (int w = 0; w < 4; ++w) outsum[s][w] = 0.f;

    #pragma unroll 1
    for (int cc = 0; cc < 2; ++cc) {
        const int c = chalf * 2 + cc;
        const float* xrow = x + (((b << 2) + c) * 64 + 2 * ix) * 64 + 2 * iy0;
        float4 a0 = *(const float4*)(xrow);
        float4 a1 = *(const float4*)(xrow + 4);
        float4 b0 = *(const float4*)(xrow + 64);
        float4 b1 = *(const float4*)(xrow + 68);

        float r0[16], r1[16], r2[16], r3[16];
        BUILD_R(r0, a0.x, a0.y, b0.x, b0.y);
        BUILD_R(r1, a0.z, a0.w, b0.z, b0.w);
        BUILD_R(r2, a1.x, a1.y, b1.x, b1.y);
        BUILD_R(r3, a1.z, a1.w, b1.z, b1.w);

        float tq[4][4];
        #pragma unroll
        for (int s = 0; s < 4; ++s)
            #pragma unroll
            for (int w = 0; w < 4; ++w) tq[s][w] = 0.f;

        #pragma unroll
        for (int jj = 0; jj < 16; ++jj) {
            float yr0 = 0.f, yi0 = 0.f, yr1 = 0.f, yi1 = 0.f;
            float yr2 = 0.f, yi2 = 0.f, yr3 = 0.f, yi3 = 0.f;
            #pragma unroll
            for (int kk = 0; kk < 8; ++kk) {
                float4 wv = Wlds[cc][jj][kk];   // broadcast ds_read_b128
                SITE_FMA(r0, yr0, yi0)
                SITE_FMA(r1, yr1, yi1)
                SITE_FMA(r2, yr2, yi2)
                SITE_FMA(r3, yr3, yi3)
            }
            float q0 = fmaf(yr0, yr0, yi0 * yi0);
            float q1 = fmaf(yr1, yr1, yi1 * yi1);
            float q2 = fmaf(yr2, yr2, yi2 * yi2);
            float q3 = fmaf(yr3, yr3, yi3 * yi3);
            // w uses bit (3-w) of jj: add if 0, sub if 1 (compile-time signs)
            #pragma unroll
            for (int w = 0; w < 4; ++w) {
                if ((jj >> (3 - w)) & 1) {
                    tq[0][w] -= q0; tq[1][w] -= q1; tq[2][w] -= q2; tq[3][w] -= q3;
                } else {
                    tq[0][w] += q0; tq[1][w] += q1; tq[2][w] += q2; tq[3][w] += q3;
                }
            }
        }

        #pragma unroll
        for (int s = 0; s < 4; ++s)
            #pragma unroll
            for (int w = 0; w < 4; ++w)
                outsum[s][w] += acos_fast(fminf(fmaxf(tq[s][w], -1.f), 1.f));
    }

    // transpose partials through LDS: thread covers sp = 4*tid + s
    __syncthreads();   // Wlds reads done (reuse-safety) + olds write ordering
    #pragma unroll
    for (int w = 0; w < 4; ++w)
        ((float4*)olds)[w * 256 + tid] =
            make_float4(outsum[0][w], outsum[1][w], outsum[2][w], outsum[3][w]);
    __syncthreads();

    // coalesced 2-way deterministic atomics: lane-consecutive dwords
    float* obase = out + ((b * 32) + (d << 2)) * 1024;
    #pragma unroll
    for (int i = 0; i < 16; ++i)
        unsafeAtomicAdd(obase + i * 256 + tid, olds[i * 256 + tid]);
}

extern "C" void kernel_launch(void* const* d_in, const int* in_sizes, int n_in,
                              void* d_out, int out_size, void* d_ws, size_t ws_size,
                              hipStream_t stream) {
    const float* x = (const float*)d_in[0];
    const float* params = (const float*)d_in[1];
    float* out = (float*)d_out;
    float2* wp = (float2*)d_ws;   // 32 * 256 * 8 bytes = 64 KiB

    prep_kernel<<<1024, 256, 0, stream>>>(params, wp, (float4*)out);
    qconv_kernel<<<8 * 2 * 32, 256, 0, stream>>>(x, wp, out);
}